// Round 1
// baseline (880.397 us; speedup 1.0000x reference)
//
#include <hip/hip_runtime.h>
#include <hip/hip_bf16.h>

typedef short bf16x8 __attribute__((ext_vector_type(8)));
typedef float f32x4 __attribute__((ext_vector_type(4)));

#define B_SZ 8192

__device__ __forceinline__ float relu_f(float v){ return v > 0.f ? v : 0.f; }

__device__ __forceinline__ f32x4 mfma16(bf16x8 a, bf16x8 b, f32x4 c){
  return __builtin_amdgcn_mfma_f32_16x16x32_bf16(a, b, c, 0, 0, 0);
}

// ---------- weight conversion ----------
__global__ __launch_bounds__(256) void conv_f2b(const float* __restrict__ s,
                                                __hip_bfloat16* __restrict__ d, int n){
  int i = blockIdx.x * 256 + threadIdx.x;
  if (i < n) d[i] = __float2bfloat16(s[i]);
}

// top_w0 (512x415) -> bf16 padded to K=416 (pad col = 0)
__global__ __launch_bounds__(256) void conv_pad_tw0(const float* __restrict__ s,
                                                    __hip_bfloat16* __restrict__ d){
  int i = blockIdx.x * 256 + threadIdx.x;      // total 512*416
  if (i >= 512 * 416) return;
  int r = i / 416, k = i - r * 416;
  float v = (k < 415) ? s[r * 415 + k] : 0.f;
  d[i] = __float2bfloat16(v);
}

// ---------- bottom layer 0: (8192x13)@(13x512)^T + b, relu, fp32 compute ----------
__global__ __launch_bounds__(256) void bot0(const float* __restrict__ X,
    const float* __restrict__ W, const float* __restrict__ Bv,
    __hip_bfloat16* __restrict__ H){
  int n = threadIdx.x;
  int m0 = blockIdx.x * 16;
  float w0[13], w1[13];
#pragma unroll
  for (int k = 0; k < 13; k++){ w0[k] = W[n*13 + k]; w1[k] = W[(n+256)*13 + k]; }
  float b0 = Bv[n], b1 = Bv[n + 256];
  for (int mi = 0; mi < 16; mi++){
    int m = m0 + mi;
    float a0 = b0, a1 = b1;
#pragma unroll
    for (int k = 0; k < 13; k++){
      float xv = X[m*13 + k];
      a0 += xv * w0[k]; a1 += xv * w1[k];
    }
    H[(size_t)m*512 + n]       = __float2bfloat16(relu_f(a0));
    H[(size_t)m*512 + n + 256] = __float2bfloat16(relu_f(a1));
  }
}

// ---------- embedding gather + mean over L=4 ----------
__global__ __launch_bounds__(256) void embed(const int* __restrict__ I,
    const float* __restrict__ T, __hip_bfloat16* __restrict__ LY){
  int wid  = blockIdx.x * 4 + (threadIdx.x >> 6);   // 0 .. 26*8192-1
  int lane = threadIdx.x & 63;
  int t = wid >> 13;
  int b = wid & 8191;
  const int4 ix = *(const int4*)(I + ((size_t)t << 15) + (b << 2));
  const float* tab = T + (size_t)t * (100001ull * 64ull);
  float s = tab[(size_t)ix.x*64 + lane] + tab[(size_t)ix.y*64 + lane]
          + tab[(size_t)ix.z*64 + lane] + tab[(size_t)ix.w*64 + lane];
  LY[((size_t)wid << 6) + lane] = __float2bfloat16(s * 0.25f);
}

// ---------- generic MFMA GEMM: C[M,N] = relu(A[M,K] @ W[N,K]^T + bias) ----------
template<int NT>
__global__ __launch_bounds__(256) void gemm_br(const __hip_bfloat16* __restrict__ A,
    const __hip_bfloat16* __restrict__ W, const float* __restrict__ Bv,
    __hip_bfloat16* __restrict__ C, int N, int K, int ldc){
  int lane = threadIdx.x & 63;
  int wave = blockIdx.x * 4 + (threadIdx.x >> 6);
  int ntiles = N / (16 * NT);
  int mi = wave / ntiles, ni = wave % ntiles;
  int row = lane & 15, quad = lane >> 4;
  const __hip_bfloat16* Ap = A + (size_t)(mi*16 + row) * K + quad*8;
  const __hip_bfloat16* Wp[NT];
  f32x4 acc[NT];
#pragma unroll
  for (int t = 0; t < NT; t++){
    Wp[t] = W + (size_t)(ni*16*NT + t*16 + row) * K + quad*8;
    acc[t] = (f32x4){0.f, 0.f, 0.f, 0.f};
  }
  for (int k = 0; k < K; k += 32){
    bf16x8 a = *(const bf16x8*)(Ap + k);
#pragma unroll
    for (int t = 0; t < NT; t++){
      bf16x8 b = *(const bf16x8*)(Wp[t] + k);
      acc[t] = mfma16(a, b, acc[t]);
    }
  }
#pragma unroll
  for (int t = 0; t < NT; t++){
    int n = ni*16*NT + t*16 + row;
    float bn = Bv[n];
#pragma unroll
    for (int r = 0; r < 4; r++){
      int m = mi*16 + quad*4 + r;
      C[(size_t)m*ldc + n] = __float2bfloat16(relu_f(acc[t][r] + bn));
    }
  }
}

// ---------- interaction: Z = T T^T per sample, strict lower triangle -> R ----------
// T row 0 = x (stored in R[:, :64]); rows 1..26 = ly[t-1]
__global__ __launch_bounds__(256) void interact(const __hip_bfloat16* __restrict__ LY,
    __hip_bfloat16* __restrict__ R){
  int b    = blockIdx.x * 4 + (threadIdx.x >> 6);
  int lane = threadIdx.x & 63;
  int row = lane & 15, quad = lane >> 4;
  __hip_bfloat16* Rb = R + (size_t)b * 416;
  f32x4 a00 = {0,0,0,0}, a10 = {0,0,0,0}, a11 = {0,0,0,0};
#pragma unroll
  for (int k = 0; k < 64; k += 32){
    int ko = k + quad*8;
    const __hip_bfloat16* p0 = (row == 0)
        ? (const __hip_bfloat16*)(Rb + ko)
        : (LY + ((((size_t)(row - 1) << 13) + b) << 6) + ko);
    bf16x8 f0 = *(const bf16x8*)p0;
    bf16x8 f1 = {0,0,0,0,0,0,0,0};
    if (row < 11)  // global row 16+row < 27
      f1 = *(const bf16x8*)(LY + ((((size_t)(row + 15) << 13) + b) << 6) + ko);
    a00 = mfma16(f0, f0, a00);
    a10 = mfma16(f1, f0, a10);
    a11 = mfma16(f1, f1, a11);
  }
#pragma unroll
  for (int r = 0; r < 4; r++){
    { int i = quad*4 + r, j = row;
      if (i > j) Rb[64 + i*(i-1)/2 + j] = __float2bfloat16(a00[r]); }
    { int i = 16 + quad*4 + r, j = row;
      if (i < 27) Rb[64 + i*(i-1)/2 + j] = __float2bfloat16(a10[r]); }
    { int i = 16 + quad*4 + r, j = 16 + row;
      if (i < 27 && i > j) Rb[64 + i*(i-1)/2 + j] = __float2bfloat16(a11[r]); }
  }
  if (lane == 0) Rb[415] = __float2bfloat16(0.f);
}

// ---------- top layer 2: out[b] = dot(h[b], w) + bias ----------
__global__ __launch_bounds__(256) void topdot(const __hip_bfloat16* __restrict__ H,
    const float* __restrict__ W, const float* __restrict__ Bv, float* __restrict__ O){
  int b    = blockIdx.x * 4 + (threadIdx.x >> 6);
  int lane = threadIdx.x & 63;
  const __hip_bfloat16* h = H + ((size_t)b << 8) + lane*4;
  float4 wv = *(const float4*)(W + lane*4);
  float acc = __bfloat162float(h[0])*wv.x + __bfloat162float(h[1])*wv.y
            + __bfloat162float(h[2])*wv.z + __bfloat162float(h[3])*wv.w;
#pragma unroll
  for (int o = 32; o; o >>= 1) acc += __shfl_xor(acc, o, 64);
  if (lane == 0) O[b] = acc + Bv[0];
}

extern "C" void kernel_launch(void* const* d_in, const int* in_sizes, int n_in,
                              void* d_out, int out_size, void* d_ws, size_t ws_size,
                              hipStream_t stream) {
  const float* dense_x = (const float*)d_in[0];
  const int*   lS_i    = (const int*)d_in[2];
  const float* tables  = (const float*)d_in[3];
  const float* bw0 = (const float*)d_in[4];  const float* bb0 = (const float*)d_in[5];
  const float* bw1 = (const float*)d_in[6];  const float* bb1 = (const float*)d_in[7];
  const float* bw2 = (const float*)d_in[8];  const float* bb2 = (const float*)d_in[9];
  const float* tw0 = (const float*)d_in[10]; const float* tb0 = (const float*)d_in[11];
  const float* tw1 = (const float*)d_in[12]; const float* tb1 = (const float*)d_in[13];
  const float* tw2 = (const float*)d_in[14]; const float* tb2 = (const float*)d_in[15];
  float* out = (float*)d_out;
  char* ws = (char*)d_ws;

  // workspace layout (bytes), all 16B aligned
  __hip_bfloat16* w1b  = (__hip_bfloat16*)(ws + 0);         // 256*512*2   = 262144
  __hip_bfloat16* w2b  = (__hip_bfloat16*)(ws + 262144);    // 64*256*2    = 32768
  __hip_bfloat16* tw0b = (__hip_bfloat16*)(ws + 294912);    // 512*416*2   = 425984
  __hip_bfloat16* tw1b = (__hip_bfloat16*)(ws + 720896);    // 256*512*2   = 262144
  __hip_bfloat16* h0   = (__hip_bfloat16*)(ws + 983040);    // 8192*512*2  = 8388608
  __hip_bfloat16* h1   = (__hip_bfloat16*)(ws + 9371648);   // 8192*256*2  = 4194304
  __hip_bfloat16* R    = (__hip_bfloat16*)(ws + 13565952);  // 8192*416*2  = 6815744
  __hip_bfloat16* ly   = (__hip_bfloat16*)(ws + 20381696);  // 26*8192*64*2= 27262976
  __hip_bfloat16* h3   = h0;  // alias: h0 dead after bot L1
  __hip_bfloat16* h4   = h1;  // alias: h1 dead after bot L2

  // weight conversions
  conv_f2b<<<512, 256, 0, stream>>>(bw1, w1b, 256*512);
  conv_f2b<<< 64, 256, 0, stream>>>(bw2, w2b, 64*256);
  conv_pad_tw0<<<832, 256, 0, stream>>>(tw0, tw0b);
  conv_f2b<<<512, 256, 0, stream>>>(tw1, tw1b, 256*512);

  // bottom MLP layer 0 (fp32 -> bf16)
  bot0<<<512, 256, 0, stream>>>(dense_x, bw0, bb0, h0);

  // embedding gather + mean
  embed<<<26*8192/4, 256, 0, stream>>>(lS_i, tables, ly);

  // bottom L1: M=8192 N=256 K=512  -> h1
  gemm_br<4><<<512, 256, 0, stream>>>(h0, w1b, bb1, h1, 256, 512, 256);
  // bottom L2: M=8192 N=64 K=256   -> x into R[:, :64] (ldc=416)
  gemm_br<1><<<512, 256, 0, stream>>>(h1, w2b, bb2, R, 64, 256, 416);

  // interaction -> R[:, 64:415], pad R[:,415]=0
  interact<<<8192/4, 256, 0, stream>>>(ly, R);

  // top L0: M=8192 N=512 K=416 -> h3
  gemm_br<4><<<1024, 256, 0, stream>>>(R, tw0b, tb0, h3, 512, 416, 512);
  // top L1: M=8192 N=256 K=512 -> h4
  gemm_br<4><<<512, 256, 0, stream>>>(h3, tw1b, tb1, h4, 256, 512, 256);
  // top L2: N=1 dot
  topdot<<<8192/4, 256, 0, stream>>>(h4, tw2, tb2, out);

  (void)in_sizes; (void)n_in; (void)out_size; (void)ws_size;
}

// Round 2
// 846.189 us; speedup vs baseline: 1.0404x; 1.0404x over previous
//
#include <hip/hip_runtime.h>
#include <hip/hip_bf16.h>

typedef short bf16x8 __attribute__((ext_vector_type(8)));
typedef float f32x4 __attribute__((ext_vector_type(4)));

__device__ __forceinline__ float relu_f(float v){ return v > 0.f ? v : 0.f; }

__device__ __forceinline__ f32x4 mfma16(bf16x8 a, bf16x8 b, f32x4 c){
  return __builtin_amdgcn_mfma_f32_16x16x32_bf16(a, b, c, 0, 0, 0);
}

__device__ __forceinline__ short bfbits(float v){
  __hip_bfloat16 h = __float2bfloat16(v);
  return *reinterpret_cast<short*>(&h);
}

// ---------- prep: all weight conversions + bottom layer 0, one kernel ----------
// blocks [0,512): bot0   (8192x13 @ 13x512^T + b, relu, fp32 -> bf16)
// blocks [512,1024): bw1 -> bf16 (256x512)
// blocks [1024,1088): bw2 -> bf16 (64x256)
// blocks [1088,1920): tw0 -> bf16 padded K 415->416
// blocks [1920,2432): tw1 -> bf16 (256x512)
__global__ __launch_bounds__(256) void prep(
    const float* __restrict__ X,  const float* __restrict__ bw0,
    const float* __restrict__ bb0, __hip_bfloat16* __restrict__ H,
    const float* __restrict__ bw1, __hip_bfloat16* __restrict__ w1b,
    const float* __restrict__ bw2, __hip_bfloat16* __restrict__ w2b,
    const float* __restrict__ tw0, __hip_bfloat16* __restrict__ tw0b,
    const float* __restrict__ tw1, __hip_bfloat16* __restrict__ tw1b){
  int blk = blockIdx.x;
  if (blk < 512){
    int n = threadIdx.x;
    int m0 = blk * 16;
    float w0[13], w1[13];
#pragma unroll
    for (int k = 0; k < 13; k++){ w0[k] = bw0[n*13 + k]; w1[k] = bw0[(n+256)*13 + k]; }
    float b0 = bb0[n], b1 = bb0[n + 256];
    for (int mi = 0; mi < 16; mi++){
      int m = m0 + mi;
      float a0 = b0, a1 = b1;
#pragma unroll
      for (int k = 0; k < 13; k++){
        float xv = X[m*13 + k];
        a0 += xv * w0[k]; a1 += xv * w1[k];
      }
      H[(size_t)m*512 + n]       = __float2bfloat16(relu_f(a0));
      H[(size_t)m*512 + n + 256] = __float2bfloat16(relu_f(a1));
    }
  } else if (blk < 1024){
    int i = (blk - 512)*256 + threadIdx.x;
    w1b[i] = __float2bfloat16(bw1[i]);
  } else if (blk < 1088){
    int i = (blk - 1024)*256 + threadIdx.x;
    w2b[i] = __float2bfloat16(bw2[i]);
  } else if (blk < 1920){
    int i = (blk - 1088)*256 + threadIdx.x;   // 512*416 = 832 blocks exactly
    int r = i / 416, k = i - r*416;
    float v = (k < 415) ? tw0[r*415 + k] : 0.f;
    tw0b[i] = __float2bfloat16(v);
  } else {
    int i = (blk - 1920)*256 + threadIdx.x;
    tw1b[i] = __float2bfloat16(tw1[i]);
  }
}

// ---------- generic MFMA GEMM: C[M,N] = relu(A[M,K] @ W[N,K]^T + bias) ----------
// compile-time K: full unroll -> compiler pipelines loads across k-iterations
template<int NT, int K>
__global__ __launch_bounds__(256) void gemm_br(const __hip_bfloat16* __restrict__ A,
    const __hip_bfloat16* __restrict__ W, const float* __restrict__ Bv,
    __hip_bfloat16* __restrict__ C, int N, int ldc){
  int lane = threadIdx.x & 63;
  int wave = blockIdx.x * 4 + (threadIdx.x >> 6);
  int ntiles = N / (16 * NT);
  int mi = wave / ntiles, ni = wave % ntiles;
  int row = lane & 15, quad = lane >> 4;
  const __hip_bfloat16* Ap = A + (size_t)(mi*16 + row) * K + quad*8;
  const __hip_bfloat16* Wp = W + (size_t)(ni*16*NT + row) * K + quad*8;
  f32x4 acc[NT];
#pragma unroll
  for (int t = 0; t < NT; t++) acc[t] = (f32x4){0.f, 0.f, 0.f, 0.f};
#pragma unroll
  for (int k = 0; k < K; k += 32){
    bf16x8 a = *(const bf16x8*)(Ap + k);
#pragma unroll
    for (int t = 0; t < NT; t++){
      bf16x8 b = *(const bf16x8*)(Wp + (size_t)t*16*K + k);
      acc[t] = mfma16(a, b, acc[t]);
    }
  }
#pragma unroll
  for (int t = 0; t < NT; t++){
    int n = ni*16*NT + t*16 + row;
    float bn = Bv[n];
#pragma unroll
    for (int r = 0; r < 4; r++){
      int m = mi*16 + quad*4 + r;
      C[(size_t)m*ldc + n] = __float2bfloat16(relu_f(acc[t][r] + bn));
    }
  }
}

// ---------- fused embedding gather/mean + interaction ----------
// one wave per sample. T-feature row 0 = x (R[b, :64], bf16), rows 1..26 =
// mean over L=4 of table rows, computed straight into MFMA A/B fragments.
__global__ __launch_bounds__(256) void embint(const int* __restrict__ I,
    const float* __restrict__ T, __hip_bfloat16* __restrict__ R){
  int b    = blockIdx.x * 4 + (threadIdx.x >> 6);
  int lane = threadIdx.x & 63;
  int row = lane & 15, quad = lane >> 4;
  __hip_bfloat16* Rb = R + (size_t)b * 416;

  int4 ix0 = {0,0,0,0}, ix1 = {0,0,0,0};
  if (row >= 1) ix0 = *(const int4*)(I + ((size_t)(row - 1) << 15) + (b << 2));
  if (row < 11) ix1 = *(const int4*)(I + ((size_t)(row + 15) << 15) + (b << 2));

  f32x4 a00 = {0,0,0,0}, a10 = {0,0,0,0}, a11 = {0,0,0,0};
#pragma unroll
  for (int k = 0; k < 64; k += 32){
    int ko = k + quad*8;
    bf16x8 f0, f1 = {0,0,0,0,0,0,0,0};
    if (row == 0){
      f0 = *(const bf16x8*)(Rb + ko);
    } else {
      const float* tb = T + (size_t)(row - 1) * 6400064ull + ko;  // 100001*64
      float s[8] = {0,0,0,0,0,0,0,0};
      int idx[4] = {ix0.x, ix0.y, ix0.z, ix0.w};
#pragma unroll
      for (int l = 0; l < 4; l++){
        const float* p = tb + (size_t)idx[l]*64;
        float4 u = *(const float4*)p;
        float4 v = *(const float4*)(p + 4);
        s[0]+=u.x; s[1]+=u.y; s[2]+=u.z; s[3]+=u.w;
        s[4]+=v.x; s[5]+=v.y; s[6]+=v.z; s[7]+=v.w;
      }
#pragma unroll
      for (int j = 0; j < 8; j++) f0[j] = bfbits(s[j]*0.25f);
    }
    if (row < 11){
      const float* tb = T + (size_t)(row + 15) * 6400064ull + ko;
      float s[8] = {0,0,0,0,0,0,0,0};
      int idx[4] = {ix1.x, ix1.y, ix1.z, ix1.w};
#pragma unroll
      for (int l = 0; l < 4; l++){
        const float* p = tb + (size_t)idx[l]*64;
        float4 u = *(const float4*)p;
        float4 v = *(const float4*)(p + 4);
        s[0]+=u.x; s[1]+=u.y; s[2]+=u.z; s[3]+=u.w;
        s[4]+=v.x; s[5]+=v.y; s[6]+=v.z; s[7]+=v.w;
      }
#pragma unroll
      for (int j = 0; j < 8; j++) f1[j] = bfbits(s[j]*0.25f);
    }
    a00 = mfma16(f0, f0, a00);
    a10 = mfma16(f1, f0, a10);
    a11 = mfma16(f1, f1, a11);
  }
#pragma unroll
  for (int r = 0; r < 4; r++){
    { int i = quad*4 + r, j = row;
      if (i > j) Rb[64 + i*(i-1)/2 + j] = __float2bfloat16(a00[r]); }
    { int i = 16 + quad*4 + r, j = row;
      if (i < 27) Rb[64 + i*(i-1)/2 + j] = __float2bfloat16(a10[r]); }
    { int i = 16 + quad*4 + r, j = 16 + row;
      if (i < 27 && i > j) Rb[64 + i*(i-1)/2 + j] = __float2bfloat16(a11[r]); }
  }
  if (lane == 0) Rb[415] = __float2bfloat16(0.f);
}

// ---------- fused top L1 gemm + final dot ----------
// block = 16 rows; wave w handles cols [w*64, w*64+64); epilogue folds
// relu(h+b) * w2 and reduces to out[m] without materializing h4.
template<int K>
__global__ __launch_bounds__(256) void top12(const __hip_bfloat16* __restrict__ A,
    const __hip_bfloat16* __restrict__ W, const float* __restrict__ Bv,
    const float* __restrict__ W2, const float* __restrict__ b2,
    float* __restrict__ O){
  __shared__ float part[4][16];
  int lane = threadIdx.x & 63, wv = threadIdx.x >> 6;
  int mi = blockIdx.x;
  int row = lane & 15, quad = lane >> 4;
  const __hip_bfloat16* Ap = A + (size_t)(mi*16 + row) * K + quad*8;
  int nb = wv * 64;
  const __hip_bfloat16* Wp = W + (size_t)(nb + row) * K + quad*8;
  f32x4 acc[4];
#pragma unroll
  for (int t = 0; t < 4; t++) acc[t] = (f32x4){0.f, 0.f, 0.f, 0.f};
#pragma unroll
  for (int k = 0; k < K; k += 32){
    bf16x8 a = *(const bf16x8*)(Ap + k);
#pragma unroll
    for (int t = 0; t < 4; t++){
      bf16x8 b = *(const bf16x8*)(Wp + (size_t)t*16*K + k);
      acc[t] = mfma16(a, b, acc[t]);
    }
  }
  float p[4];
#pragma unroll
  for (int r = 0; r < 4; r++){
    float s = 0.f;
#pragma unroll
    for (int t = 0; t < 4; t++){
      int n = nb + t*16 + row;
      s += relu_f(acc[t][r] + Bv[n]) * W2[n];
    }
    p[r] = s;
  }
#pragma unroll
  for (int r = 0; r < 4; r++){
#pragma unroll
    for (int o = 1; o < 16; o <<= 1) p[r] += __shfl_xor(p[r], o, 64);
  }
  if (row == 0){
#pragma unroll
    for (int r = 0; r < 4; r++) part[wv][quad*4 + r] = p[r];
  }
  __syncthreads();
  if (threadIdx.x < 16){
    float s = part[0][threadIdx.x] + part[1][threadIdx.x]
            + part[2][threadIdx.x] + part[3][threadIdx.x] + b2[0];
    O[mi*16 + threadIdx.x] = s;
  }
}

extern "C" void kernel_launch(void* const* d_in, const int* in_sizes, int n_in,
                              void* d_out, int out_size, void* d_ws, size_t ws_size,
                              hipStream_t stream) {
  const float* dense_x = (const float*)d_in[0];
  const int*   lS_i    = (const int*)d_in[2];
  const float* tables  = (const float*)d_in[3];
  const float* bw0 = (const float*)d_in[4];  const float* bb0 = (const float*)d_in[5];
  const float* bw1 = (const float*)d_in[6];  const float* bb1 = (const float*)d_in[7];
  const float* bw2 = (const float*)d_in[8];  const float* bb2 = (const float*)d_in[9];
  const float* tw0 = (const float*)d_in[10]; const float* tb0 = (const float*)d_in[11];
  const float* tw1 = (const float*)d_in[12]; const float* tb1 = (const float*)d_in[13];
  const float* tw2 = (const float*)d_in[14]; const float* tb2 = (const float*)d_in[15];
  float* out = (float*)d_out;
  char* ws = (char*)d_ws;

  // workspace layout (bytes), 16B aligned
  __hip_bfloat16* w1b  = (__hip_bfloat16*)(ws + 0);         // 256*512*2
  __hip_bfloat16* w2b  = (__hip_bfloat16*)(ws + 262144);    // 64*256*2
  __hip_bfloat16* tw0b = (__hip_bfloat16*)(ws + 294912);    // 512*416*2
  __hip_bfloat16* tw1b = (__hip_bfloat16*)(ws + 720896);    // 256*512*2
  __hip_bfloat16* h0   = (__hip_bfloat16*)(ws + 983040);    // 8192*512*2
  __hip_bfloat16* h1   = (__hip_bfloat16*)(ws + 9371648);   // 8192*256*2
  __hip_bfloat16* R    = (__hip_bfloat16*)(ws + 13565952);  // 8192*416*2
  __hip_bfloat16* h3   = h0;  // h0 dead after bot L1

  // 1. all weight conversions + bottom L0
  prep<<<2432, 256, 0, stream>>>(dense_x, bw0, bb0, h0,
                                 bw1, w1b, bw2, w2b, tw0, tw0b, tw1, tw1b);
  // 2. bottom L1: M=8192 N=256 K=512 -> h1
  gemm_br<4,512><<<512, 256, 0, stream>>>(h0, w1b, bb1, h1, 256, 256);
  // 3. bottom L2: M=8192 N=64 K=256 -> x into R[:, :64] (ldc=416)
  gemm_br<1,256><<<512, 256, 0, stream>>>(h1, w2b, bb2, R, 64, 416);
  // 4. fused embedding + interaction -> R[:, 64:415], pad R[:,415]=0
  embint<<<8192/4, 256, 0, stream>>>(lS_i, tables, R);
  // 5. top L0: M=8192 N=512 K=416 -> h3
  gemm_br<4,416><<<1024, 256, 0, stream>>>(R, tw0b, tb0, h3, 512, 512);
  // 6. top L1 + final dot -> out
  top12<512><<<512, 256, 0, stream>>>(h3, tw1b, tb1, tw2, tb2, out);

  (void)in_sizes; (void)n_in; (void)out_size; (void)ws_size;
}